// Round 13
// baseline (73.315 us; speedup 1.0000x reference)
//
#include <hip/hip_runtime.h>

typedef _Float16 f16x8 __attribute__((ext_vector_type(8)));
typedef float f32x16 __attribute__((ext_vector_type(16)));
typedef float f32x2v __attribute__((ext_vector_type(2)));
typedef unsigned u32x2v __attribute__((ext_vector_type(2)));

static __device__ __forceinline__ unsigned cvtpk_u(float a, float b) {
    unsigned r;
    asm("v_cvt_pkrtz_f16_f32 %0, %1, %2" : "=v"(r) : "v"(a), "v"(b));
    return r;
}
static __device__ __forceinline__ f16x8 mk_frag(unsigned a, unsigned b, unsigned c, unsigned d) {
    union { unsigned u[4]; f16x8 v; } x;
    x.u[0]=a; x.u[1]=b; x.u[2]=c; x.u[3]=d; return x.v;
}

// Coefficient bundle (built once in the kernel, passed by value so the
// constants live in registers, never rematerialized per call).
struct TC { f32x2v c2n, c1n, c0, c2d, c1d; };

// Packed Pade(5,4) tanh on pk-f32 — no trans ops, no division.
// tanh x ~= x*((u/64)*u + 105/64)*u + 945/64) / (((15/64)*u + 420/64)*u + 945/64)
// u = x^2; magic-rcp + 1 Newton (undershoot <= ~0.4%); med3 clamp (t>=1 for
// x>=3.8, poly HW-anchored by R7). f32 range: no input clamp needed.
static __device__ __forceinline__ f32x2v tanh2(f32x2v x, const TC& k) {
    f32x2v u = x * x;
    f32x2v n = (u * k.c2n + k.c1n) * u + k.c0;
    f32x2v d = (u * k.c2d + k.c1d) * u + k.c0;
    u32x2v di = __builtin_bit_cast(u32x2v, d);
    u32x2v r0i = 0x7EF127EAu - di;
    f32x2v r0 = __builtin_bit_cast(f32x2v, r0i);
    f32x2v r = r0 * (-d * r0 + 2.0f);
    f32x2v t = x * n * r;
    f32x2v o;
    o[0] = __builtin_amdgcn_fmed3f(t[0], -1.0f, 1.0f);
    o[1] = __builtin_amdgcn_fmed3f(t[1], -1.0f, 1.0f);
    return o;
}

// One L2 bank: acc = W2^T @ h + b2 from 8 packed f16 tanh pairs.
static __device__ __forceinline__ f32x16 l2_bank(const unsigned* P,
        f16x8 A20, f16x8 A21, const f32x16& b2v)
{
    auto u02 = __builtin_amdgcn_permlane32_swap((int)P[0], (int)P[2], false, false);
    auto u13 = __builtin_amdgcn_permlane32_swap((int)P[1], (int)P[3], false, false);
    f16x8 Bq = mk_frag((unsigned)u02[0], (unsigned)u13[0], (unsigned)u02[1], (unsigned)u13[1]);
    f32x16 a = __builtin_amdgcn_mfma_f32_32x32x16_f16(A20, Bq, b2v, 0, 0, 0);
    auto v02 = __builtin_amdgcn_permlane32_swap((int)P[4], (int)P[6], false, false);
    auto v13 = __builtin_amdgcn_permlane32_swap((int)P[5], (int)P[7], false, false);
    f16x8 Br = mk_frag((unsigned)v02[0], (unsigned)v13[0], (unsigned)v02[1], (unsigned)v13[1]);
    return __builtin_amdgcn_mfma_f32_32x32x16_f16(A21, Br, a, 0, 0, 0);
}

static __device__ __forceinline__ f32x2v pick2(const f32x16& v, int m) {
    f32x2v r; r[0] = v[2*m]; r[1] = v[2*m+1]; return r;
}

// Two-element MLP; e/g hold elem0 in .0, elem1 in .1. All tanh direct
// (raw weights; no sigma folding).
static __device__ __forceinline__ f32x2v mlp_f2(f32x2v e, f32x2v g,
        f16x8 A1, const f32x16& b1v,
        f16x8 A20, f16x8 A21, const f32x16& b2v,
        const f32x16& w3v, float b3v, const TC& k)
{
    unsigned wA = cvtpk_u(e[0], g[0]);
    unsigned wB = cvtpk_u(e[1], g[1]);
    auto sA = __builtin_amdgcn_permlane32_swap((int)wA, 0, false, false);
    auto sB = __builtin_amdgcn_permlane32_swap((int)wB, 0, false, false);
    f32x16 d1a = __builtin_amdgcn_mfma_f32_32x32x16_f16(A1, mk_frag((unsigned)sA[0],0u,0u,0u), b1v, 0, 0, 0);
    f32x16 d2a = __builtin_amdgcn_mfma_f32_32x32x16_f16(A1, mk_frag((unsigned)sA[1],0u,0u,0u), b1v, 0, 0, 0);
    f32x16 d1b = __builtin_amdgcn_mfma_f32_32x32x16_f16(A1, mk_frag((unsigned)sB[0],0u,0u,0u), b1v, 0, 0, 0);
    f32x16 d2b = __builtin_amdgcn_mfma_f32_32x32x16_f16(A1, mk_frag((unsigned)sB[1],0u,0u,0u), b1v, 0, 0, 0);

    unsigned Pa[8], Qa[8], Pb[8], Qb[8];
#pragma unroll
    for (int m = 0; m < 8; ++m) {
        f32x2v t0 = tanh2(pick2(d1a, m), k);  Pa[m] = cvtpk_u(t0[0], t0[1]);
        f32x2v t1 = tanh2(pick2(d2a, m), k);  Qa[m] = cvtpk_u(t1[0], t1[1]);
        f32x2v t2 = tanh2(pick2(d1b, m), k);  Pb[m] = cvtpk_u(t2[0], t2[1]);
        f32x2v t3 = tanh2(pick2(d2b, m), k);  Qb[m] = cvtpk_u(t3[0], t3[1]);
    }

    f32x16 a1a = l2_bank(Pa, A20, A21, b2v);
    f32x16 a2a = l2_bank(Qa, A20, A21, b2v);
    f32x16 a1b = l2_bank(Pb, A20, A21, b2v);
    f32x16 a2b = l2_bank(Qb, A20, A21, b2v);

    f32x2v accAa = {0.0f,0.0f}, accBa = {0.0f,0.0f};
    f32x2v accAb = {0.0f,0.0f}, accBb = {0.0f,0.0f};
#pragma unroll
    for (int m = 0; m < 8; ++m) {
        f32x2v wp; wp[0] = w3v[2*m]; wp[1] = w3v[2*m+1];
        accAa = wp * tanh2(pick2(a1a, m), k) + accAa;
        accBa = wp * tanh2(pick2(a2a, m), k) + accBa;
        accAb = wp * tanh2(pick2(a1b, m), k) + accAb;
        accBb = wp * tanh2(pick2(a2b, m), k) + accBb;
    }
    float pAa = accAa[0] + accAa[1], pBa = accBa[0] + accBa[1];
    float pAb = accAb[0] + accAb[1], pBb = accBb[0] + accBb[1];
    auto ca = __builtin_amdgcn_permlane32_swap(__float_as_int(pAa), __float_as_int(pBa), false, false);
    auto cb = __builtin_amdgcn_permlane32_swap(__float_as_int(pAb), __float_as_int(pBb), false, false);
    float oa = b3v + __int_as_float(ca[0]) + __int_as_float(ca[1]);
    float ob = b3v + __int_as_float(cb[0]) + __int_as_float(cb[1]);
    f32x2v out;
    out[0] = __logf(1.0f + __expf(oa));   // softplus; |o| <~ 6
    out[1] = __logf(1.0f + __expf(ob));
    return out;
}

__global__ __launch_bounds__(256) void gamma_rk4_mfma(
        const float4* __restrict__ inp, const float* __restrict__ gamma,
        const float* __restrict__ W1, const float* __restrict__ b1,
        const float* __restrict__ W2, const float* __restrict__ b2,
        const float* __restrict__ W3, const float* __restrict__ b3,
        float* __restrict__ out, int B)
{
    int idx  = blockIdx.x * 256 + threadIdx.x;
    int lane = threadIdx.x & 63;
    int hi   = lane >> 5;
    int arow = lane & 31;

    TC k;
    k.c2n = f32x2v{0.015625f, 0.015625f};    // 1/64
    k.c1n = f32x2v{1.640625f, 1.640625f};    // 105/64
    k.c0  = f32x2v{14.765625f, 14.765625f};  // 945/64
    k.c2d = f32x2v{0.234375f, 0.234375f};    // 15/64
    k.c1d = f32x2v{6.5625f, 6.5625f};        // 420/64

    // L1 A-frag: raw W1 in f16; k0=W1[0][j], k1=W1[1][j]; hi lanes zero
    f16x8 A1;
    {
        unsigned p10 = cvtpk_u(W1[arow], W1[32 + arow]);
        A1 = hi ? mk_frag(0u, 0u, 0u, 0u) : mk_frag(p10, 0u, 0u, 0u);
    }
    // L2 A = raw W2^T in f16 (two K=16 chunks): A[j][k] = W2[k][j]
    f16x8 A2[2];
#pragma unroll
    for (int s = 0; s < 2; ++s) {
        unsigned w[4];
#pragma unroll
        for (int m = 0; m < 4; ++m) {
            w[m] = cvtpk_u(W2[(16*s + 8*hi + 2*m    ) * 32 + arow],
                           W2[(16*s + 8*hi + 2*m + 1) * 32 + arow]);
        }
        A2[s] = mk_frag(w[0], w[1], w[2], w[3]);
    }
    // C/D row map: row = (r&3) + 8*(r>>2) + 4*hi
    f32x16 b1v, b2v, w3v;
#pragma unroll
    for (int r = 0; r < 16; ++r) {
        int row = (r & 3) + 8 * (r >> 2) + 4 * hi;
        b1v[r] = b1[row];
        b2v[r] = b2[row];
        w3v[r] = W3[row];
    }
    float b3v = b3[0];

    int i0 = 2 * idx;
    if (i0 >= B) return;
    float4 va = inp[i0];
    float4 vb = inp[i0 + 1];
    float2 gg = *reinterpret_cast<const float2*>(gamma + i0);

    f32x2v g0v = {gg.x, gg.y};
    f32x2v e_n = {va.x, vb.x}, e_h = {va.y, vb.y}, e_o = {va.z, vb.z};
    f32x2v dt  = {va.w, vb.w};

    f32x2v k1 = dt * mlp_f2(e_n, g0v, A1, b1v, A2[0], A2[1], b2v, w3v, b3v, k) * (e_n - g0v);
    f32x2v g1 = 0.5f * k1 + g0v;
    f32x2v k2 = dt * mlp_f2(e_h, g1,  A1, b1v, A2[0], A2[1], b2v, w3v, b3v, k) * (e_h - g1);
    f32x2v g2 = 0.5f * k2 + g0v;
    f32x2v k3 = dt * mlp_f2(e_h, g2,  A1, b1v, A2[0], A2[1], b2v, w3v, b3v, k) * (e_h - g2);
    f32x2v g3 = g0v + k3;
    f32x2v k4 = dt * mlp_f2(e_o, g3,  A1, b1v, A2[0], A2[1], b2v, w3v, b3v, k) * (e_o - g3);

    f32x2v res = g0v + (k1 + 2.0f * (k2 + k3) + k4) * (1.0f / 6.0f);
    float2 ro; ro.x = res[0]; ro.y = res[1];
    *reinterpret_cast<float2*>(out + i0) = ro;
}

extern "C" void kernel_launch(void* const* d_in, const int* in_sizes, int n_in,
                              void* d_out, int out_size, void* d_ws, size_t ws_size,
                              hipStream_t stream) {
    const float4* inp   = (const float4*)d_in[0];
    const float*  gamma = (const float*)d_in[1];
    const float*  W1    = (const float*)d_in[2];
    const float*  b1    = (const float*)d_in[3];
    const float*  W2    = (const float*)d_in[4];
    const float*  b2    = (const float*)d_in[5];
    const float*  W3    = (const float*)d_in[6];
    const float*  b3    = (const float*)d_in[7];
    float* out = (float*)d_out;

    int B = in_sizes[1];
    int threads = (B + 1) / 2;
    int block = 256;
    int grid = (threads + block - 1) / block;
    gamma_rk4_mfma<<<grid, block, 0, stream>>>(inp, gamma, W1, b1, W2, b2,
                                               W3, b3, out, B);
}

// Round 14
// 62.666 us; speedup vs baseline: 1.1699x; 1.1699x over previous
//
#include <hip/hip_runtime.h>

typedef _Float16 f16x8 __attribute__((ext_vector_type(8)));
typedef float f32x16 __attribute__((ext_vector_type(16)));
typedef float f32x2v __attribute__((ext_vector_type(2)));
typedef unsigned u32x2v __attribute__((ext_vector_type(2)));

#define C2LE 2.8853900817779268f     // 2*log2(e)
#define NEG2C (-5.7707801635558537f) // -2*C2LE

static __device__ __forceinline__ unsigned cvtpk_u(float a, float b) {
    unsigned r;
    asm("v_cvt_pkrtz_f16_f32 %0, %1, %2" : "=v"(r) : "v"(a), "v"(b));
    return r;
}
static __device__ __forceinline__ float exp2_r(float x) {
    float r; asm("v_exp_f32 %0, %1" : "=v"(r) : "v"(x)); return r;
}
static __device__ __forceinline__ f16x8 mk_frag(unsigned a, unsigned b, unsigned c, unsigned d) {
    union { unsigned u[4]; f16x8 v; } x;
    x.u[0]=a; x.u[1]=b; x.u[2]=c; x.u[3]=d; return x.v;
}

// Pade coefficients for sigma-from-scaled-arg (d = c*pre, c = 2*log2 e):
// t = tanh(pre) = d * Nh(v)/Dh(v), v = d^2, coeffs pre-divided by c^k.
struct PC { f32x2v n2, n1, n0, d2, d1, d0; };

// TRANS-pipe sigma: r = 1/(1+2^x). 2 exp2 (trans) + pk-f32 magic-NR.
static __device__ __forceinline__ f32x2v sigp(float a, float b) {
    f32x2v E; E[0] = exp2_r(a); E[1] = exp2_r(b);
    f32x2v d = E + 1.0f;
    u32x2v di = __builtin_bit_cast(u32x2v, d);
    u32x2v r0i = 0x7EF127EAu - di;
    f32x2v r0 = __builtin_bit_cast(f32x2v, r0i);
    f32x2v s = -d * r0 + 2.0f;
    return r0 * s;
}

// MAIN-pipe sigma: Pade(5,4) tanh on pk-f32 then r = 0.5 - 0.5 t.
// No trans ops. Poly HW-anchored (R7); magic+1NR rcp (accepted since R6).
static __device__ __forceinline__ f32x2v sigp_pade(f32x2v d, const PC& k) {
    f32x2v v = d * d;
    f32x2v n = (v * k.n2 + k.n1) * v + k.n0;
    f32x2v q = (v * k.d2 + k.d1) * v + k.d0;
    u32x2v qi = __builtin_bit_cast(u32x2v, q);
    u32x2v r0i = 0x7EF127EAu - qi;
    f32x2v r0 = __builtin_bit_cast(f32x2v, r0i);
    f32x2v r = r0 * (-q * r0 + 2.0f);
    f32x2v t = d * n * r;
    f32x2v o;
    o[0] = __builtin_amdgcn_fmed3f(t[0], -1.0f, 1.0f);
    o[1] = __builtin_amdgcn_fmed3f(t[1], -1.0f, 1.0f);
    return o * -0.5f + 0.5f;
}

static __device__ __forceinline__ f32x16 l2_bank(const unsigned* P,
        f16x8 A20, f16x8 A21, const f32x16& cb2v)
{
    auto u02 = __builtin_amdgcn_permlane32_swap((int)P[0], (int)P[2], false, false);
    auto u13 = __builtin_amdgcn_permlane32_swap((int)P[1], (int)P[3], false, false);
    f16x8 Bq = mk_frag((unsigned)u02[0], (unsigned)u13[0], (unsigned)u02[1], (unsigned)u13[1]);
    f32x16 a = __builtin_amdgcn_mfma_f32_32x32x16_f16(A20, Bq, cb2v, 0, 0, 0);
    auto v02 = __builtin_amdgcn_permlane32_swap((int)P[4], (int)P[6], false, false);
    auto v13 = __builtin_amdgcn_permlane32_swap((int)P[5], (int)P[7], false, false);
    f16x8 Br = mk_frag((unsigned)v02[0], (unsigned)v13[0], (unsigned)v02[1], (unsigned)v13[1]);
    return __builtin_amdgcn_mfma_f32_32x32x16_f16(A21, Br, a, 0, 0, 0);
}

static __device__ __forceinline__ f32x2v pick2(const f32x16& v, int m) {
    f32x2v r; r[0] = v[2*m]; r[1] = v[2*m+1]; return r;
}

// Two-element MLP; sigma-folded network (A' = -2c*W2^T etc).
// 3/4 of sigmas on the trans pipe (sigp), 1/4 on the main pipe (sigp_pade).
static __device__ __forceinline__ f32x2v mlp_f2(f32x2v e, f32x2v g,
        f16x8 A1, const f32x16& cb1v,
        f16x8 A20, f16x8 A21, const f32x16& cb2v,
        const f32x16& w3m, float o0, const PC& k)
{
    unsigned wA = cvtpk_u(e[0], g[0]);
    unsigned wB = cvtpk_u(e[1], g[1]);
    auto sA = __builtin_amdgcn_permlane32_swap((int)wA, 0, false, false);
    auto sB = __builtin_amdgcn_permlane32_swap((int)wB, 0, false, false);
    f32x16 d1a = __builtin_amdgcn_mfma_f32_32x32x16_f16(A1, mk_frag((unsigned)sA[0],0u,0u,0u), cb1v, 0, 0, 0);
    f32x16 d2a = __builtin_amdgcn_mfma_f32_32x32x16_f16(A1, mk_frag((unsigned)sA[1],0u,0u,0u), cb1v, 0, 0, 0);
    f32x16 d1b = __builtin_amdgcn_mfma_f32_32x32x16_f16(A1, mk_frag((unsigned)sB[0],0u,0u,0u), cb1v, 0, 0, 0);
    f32x16 d2b = __builtin_amdgcn_mfma_f32_32x32x16_f16(A1, mk_frag((unsigned)sB[1],0u,0u,0u), cb1v, 0, 0, 0);

    unsigned Pa[8], Qa[8], Pb[8], Qb[8];
#pragma unroll
    for (int m = 0; m < 8; ++m) {
        f32x2v r0 = sigp(d1a[2*m], d1a[2*m+1]);      Pa[m] = cvtpk_u(r0[0], r0[1]);
        f32x2v r1 = sigp(d2a[2*m], d2a[2*m+1]);      Qa[m] = cvtpk_u(r1[0], r1[1]);
        f32x2v r2 = sigp(d1b[2*m], d1b[2*m+1]);      Pb[m] = cvtpk_u(r2[0], r2[1]);
        f32x2v r3 = sigp_pade(pick2(d2b, m), k);     Qb[m] = cvtpk_u(r3[0], r3[1]);  // main pipe
    }

    f32x16 a1a = l2_bank(Pa, A20, A21, cb2v);
    f32x16 a2a = l2_bank(Qa, A20, A21, cb2v);
    f32x16 a1b = l2_bank(Pb, A20, A21, cb2v);
    f32x16 a2b = l2_bank(Qb, A20, A21, cb2v);

    f32x2v accAa = {0.0f,0.0f}, accBa = {0.0f,0.0f};
    f32x2v accAb = {0.0f,0.0f}, accBb = {0.0f,0.0f};
#pragma unroll
    for (int m = 0; m < 8; ++m) {
        f32x2v wp; wp[0] = w3m[2*m]; wp[1] = w3m[2*m+1];
        accAa = wp * sigp(a1a[2*m], a1a[2*m+1]) + accAa;
        accBa = wp * sigp(a2a[2*m], a2a[2*m+1]) + accBa;
        accAb = wp * sigp(a1b[2*m], a1b[2*m+1]) + accAb;
        accBb = wp * sigp_pade(pick2(a2b, m), k) + accBb;   // main pipe
    }
    float pAa = accAa[0] + accAa[1], pBa = accBa[0] + accBa[1];
    float pAb = accAb[0] + accAb[1], pBb = accBb[0] + accBb[1];
    auto ca = __builtin_amdgcn_permlane32_swap(__float_as_int(pAa), __float_as_int(pBa), false, false);
    auto cb = __builtin_amdgcn_permlane32_swap(__float_as_int(pAb), __float_as_int(pBb), false, false);
    float oa = o0 + __int_as_float(ca[0]) + __int_as_float(ca[1]);
    float ob = o0 + __int_as_float(cb[0]) + __int_as_float(cb[1]);
    f32x2v out;
    out[0] = __logf(1.0f + __expf(oa));   // softplus; |o| <~ 6
    out[1] = __logf(1.0f + __expf(ob));
    return out;
}

__global__ __launch_bounds__(256) void gamma_rk4_mfma(
        const float4* __restrict__ inp, const float* __restrict__ gamma,
        const float* __restrict__ W1, const float* __restrict__ b1,
        const float* __restrict__ W2, const float* __restrict__ b2,
        const float* __restrict__ W3, const float* __restrict__ b3,
        float* __restrict__ out, int B)
{
    int idx  = blockIdx.x * 256 + threadIdx.x;
    int lane = threadIdx.x & 63;
    int hi   = lane >> 5;
    int arow = lane & 31;

    // Pade coeffs pre-scaled for d = c*pre (c=2log2e): divide by c^k.
    PC k;
    k.n2 = f32x2v{7.812492e-5f, 7.812492e-5f};   // (1/64)/c^5
    k.n1 = f32x2v{0.06829599f, 0.06829599f};     // (105/64)/c^3
    k.n0 = f32x2v{5.1173215f, 5.1173215f};       // (945/64)/c
    k.d2 = f32x2v{3.381387e-3f, 3.381387e-3f};   // (15/64)/c^4
    k.d1 = f32x2v{0.78824532f, 0.78824532f};     // (420/64)/c^2
    k.d0 = f32x2v{14.765625f, 14.765625f};       // 945/64

    // L1 A-frag: A = c*W1 in f16; hi lanes zero
    f16x8 A1;
    {
        unsigned p10 = cvtpk_u(C2LE * W1[arow], C2LE * W1[32 + arow]);
        A1 = hi ? mk_frag(0u, 0u, 0u, 0u) : mk_frag(p10, 0u, 0u, 0u);
    }
    // L2 A' = -2c*W2^T in f16 (two K=16 chunks)
    f16x8 A2[2];
#pragma unroll
    for (int s = 0; s < 2; ++s) {
        unsigned w[4];
#pragma unroll
        for (int m = 0; m < 4; ++m) {
            w[m] = cvtpk_u(NEG2C * W2[(16*s + 8*hi + 2*m    ) * 32 + arow],
                           NEG2C * W2[(16*s + 8*hi + 2*m + 1) * 32 + arow]);
        }
        A2[s] = mk_frag(w[0], w[1], w[2], w[3]);
    }
    // C/D row map: row = (r&3) + 8*(r>>2) + 4*hi
    f32x16 cb1v, cb2v, w3m;
    float wsum = 0.0f;
#pragma unroll
    for (int r = 0; r < 16; ++r) {
        int row = (r & 3) + 8 * (r >> 2) + 4 * hi;
        cb1v[r] = C2LE * b1[row];
        cb2v[r] = C2LE * b2[row];
        float w3 = W3[row];
        w3m[r] = -2.0f * w3;
        wsum  += w3;
    }
    // cb2v += c*colsum(W2) via MFMA with B = -0.5 (exact in f16: 0xB800)
    {
        unsigned nh = 0xB800B800u;
        f16x8 negh = mk_frag(nh, nh, nh, nh);
        cb2v = __builtin_amdgcn_mfma_f32_32x32x16_f16(A2[0], negh, cb2v, 0, 0, 0);
        cb2v = __builtin_amdgcn_mfma_f32_32x32x16_f16(A2[1], negh, cb2v, 0, 0, 0);
    }
    auto sw = __builtin_amdgcn_permlane32_swap(__float_as_int(wsum), __float_as_int(wsum), false, false);
    float o0 = b3[0] + __int_as_float(sw[0]) + __int_as_float(sw[1]);

    int i0 = 2 * idx;
    if (i0 >= B) return;
    float4 va = inp[i0];
    float4 vb = inp[i0 + 1];
    float2 gg = *reinterpret_cast<const float2*>(gamma + i0);

    f32x2v g0v = {gg.x, gg.y};
    f32x2v e_n = {va.x, vb.x}, e_h = {va.y, vb.y}, e_o = {va.z, vb.z};
    f32x2v dt  = {va.w, vb.w};

    f32x2v k1 = dt * mlp_f2(e_n, g0v, A1, cb1v, A2[0], A2[1], cb2v, w3m, o0, k) * (e_n - g0v);
    f32x2v g1 = 0.5f * k1 + g0v;
    f32x2v k2 = dt * mlp_f2(e_h, g1,  A1, cb1v, A2[0], A2[1], cb2v, w3m, o0, k) * (e_h - g1);
    f32x2v g2 = 0.5f * k2 + g0v;
    f32x2v k3 = dt * mlp_f2(e_h, g2,  A1, cb1v, A2[0], A2[1], cb2v, w3m, o0, k) * (e_h - g2);
    f32x2v g3 = g0v + k3;
    f32x2v k4 = dt * mlp_f2(e_o, g3,  A1, cb1v, A2[0], A2[1], cb2v, w3m, o0, k) * (e_o - g3);

    f32x2v res = g0v + (k1 + 2.0f * (k2 + k3) + k4) * (1.0f / 6.0f);
    float2 ro; ro.x = res[0]; ro.y = res[1];
    *reinterpret_cast<float2*>(out + i0) = ro;
}

extern "C" void kernel_launch(void* const* d_in, const int* in_sizes, int n_in,
                              void* d_out, int out_size, void* d_ws, size_t ws_size,
                              hipStream_t stream) {
    const float4* inp   = (const float4*)d_in[0];
    const float*  gamma = (const float*)d_in[1];
    const float*  W1    = (const float*)d_in[2];
    const float*  b1    = (const float*)d_in[3];
    const float*  W2    = (const float*)d_in[4];
    const float*  b2    = (const float*)d_in[5];
    const float*  W3    = (const float*)d_in[6];
    const float*  b3    = (const float*)d_in[7];
    float* out = (float*)d_out;

    int B = in_sizes[1];
    int threads = (B + 1) / 2;
    int block = 256;
    int grid = (threads + block - 1) / block;
    gamma_rk4_mfma<<<grid, block, 0, stream>>>(inp, gamma, W1, b1, W2, b2,
                                               W3, b3, out, B);
}

// Round 15
// 57.912 us; speedup vs baseline: 1.2660x; 1.0821x over previous
//
#include <hip/hip_runtime.h>

typedef _Float16 f16x8 __attribute__((ext_vector_type(8)));
typedef float f32x16 __attribute__((ext_vector_type(16)));
typedef float f32x2v __attribute__((ext_vector_type(2)));
typedef unsigned u32x2v __attribute__((ext_vector_type(2)));

#define C2LE 2.8853900817779268f     // 2*log2(e)
#define NEG2C (-5.7707801635558537f) // -2*C2LE

static __device__ __forceinline__ unsigned cvtpk_u(float a, float b) {
    unsigned r;
    asm("v_cvt_pkrtz_f16_f32 %0, %1, %2" : "=v"(r) : "v"(a), "v"(b));
    return r;
}
static __device__ __forceinline__ float exp2_r(float x) {
    float r; asm("v_exp_f32 %0, %1" : "=v"(r) : "v"(x)); return r;
}
static __device__ __forceinline__ f16x8 mk_frag(unsigned a, unsigned b, unsigned c, unsigned d) {
    union { unsigned u[4]; f16x8 v; } x;
    x.u[0]=a; x.u[1]=b; x.u[2]=c; x.u[3]=d; return x.v;
}

// Paired sigma: r_i = 1/(1+2^x_i); scalar exp2 (trans) + pk-f32 magic-NR rcp.
static __device__ __forceinline__ f32x2v sigp(float a, float b) {
    f32x2v E; E[0] = exp2_r(a); E[1] = exp2_r(b);
    f32x2v d = E + 1.0f;
    u32x2v di = __builtin_bit_cast(u32x2v, d);
    u32x2v r0i = 0x7EF127EAu - di;
    f32x2v r0 = __builtin_bit_cast(f32x2v, r0i);
    f32x2v s = -d * r0 + 2.0f;
    return r0 * s;
}

// One L2 bank: acc = A' @ r + cb2v from 8 packed sigma pairs.
static __device__ __forceinline__ f32x16 l2_bank(const unsigned* P,
        f16x8 A20, f16x8 A21, const f32x16& cb2v)
{
    auto u02 = __builtin_amdgcn_permlane32_swap((int)P[0], (int)P[2], false, false);
    auto u13 = __builtin_amdgcn_permlane32_swap((int)P[1], (int)P[3], false, false);
    f16x8 Bq = mk_frag((unsigned)u02[0], (unsigned)u13[0], (unsigned)u02[1], (unsigned)u13[1]);
    f32x16 a = __builtin_amdgcn_mfma_f32_32x32x16_f16(A20, Bq, cb2v, 0, 0, 0);
    auto v02 = __builtin_amdgcn_permlane32_swap((int)P[4], (int)P[6], false, false);
    auto v13 = __builtin_amdgcn_permlane32_swap((int)P[5], (int)P[7], false, false);
    f16x8 Br = mk_frag((unsigned)v02[0], (unsigned)v13[0], (unsigned)v02[1], (unsigned)v13[1]);
    return __builtin_amdgcn_mfma_f32_32x32x16_f16(A21, Br, a, 0, 0, 0);
}

// Two-element MLP: e/g hold elem0 in lane .0, elem1 in lane .1.
static __device__ __forceinline__ f32x2v mlp_f2(f32x2v e, f32x2v g,
        f16x8 A1, const f32x16& cb1v,
        f16x8 A20, f16x8 A21, const f32x16& cb2v,
        const f32x16& w3m, float o0)
{
    unsigned wA = cvtpk_u(e[0], g[0]);
    unsigned wB = cvtpk_u(e[1], g[1]);
    auto sA = __builtin_amdgcn_permlane32_swap((int)wA, 0, false, false);
    auto sB = __builtin_amdgcn_permlane32_swap((int)wB, 0, false, false);
    f32x16 d1a = __builtin_amdgcn_mfma_f32_32x32x16_f16(A1, mk_frag((unsigned)sA[0],0u,0u,0u), cb1v, 0, 0, 0);
    f32x16 d2a = __builtin_amdgcn_mfma_f32_32x32x16_f16(A1, mk_frag((unsigned)sA[1],0u,0u,0u), cb1v, 0, 0, 0);
    f32x16 d1b = __builtin_amdgcn_mfma_f32_32x32x16_f16(A1, mk_frag((unsigned)sB[0],0u,0u,0u), cb1v, 0, 0, 0);
    f32x16 d2b = __builtin_amdgcn_mfma_f32_32x32x16_f16(A1, mk_frag((unsigned)sB[1],0u,0u,0u), cb1v, 0, 0, 0);

    unsigned Pa[8], Qa[8], Pb[8], Qb[8];
#pragma unroll
    for (int m = 0; m < 8; ++m) {
        f32x2v r0 = sigp(d1a[2*m], d1a[2*m+1]);  Pa[m] = cvtpk_u(r0[0], r0[1]);
        f32x2v r1 = sigp(d2a[2*m], d2a[2*m+1]);  Qa[m] = cvtpk_u(r1[0], r1[1]);
        f32x2v r2 = sigp(d1b[2*m], d1b[2*m+1]);  Pb[m] = cvtpk_u(r2[0], r2[1]);
        f32x2v r3 = sigp(d2b[2*m], d2b[2*m+1]);  Qb[m] = cvtpk_u(r3[0], r3[1]);
    }

    f32x16 a1a = l2_bank(Pa, A20, A21, cb2v);
    f32x16 a2a = l2_bank(Qa, A20, A21, cb2v);
    f32x16 a1b = l2_bank(Pb, A20, A21, cb2v);
    f32x16 a2b = l2_bank(Qb, A20, A21, cb2v);

    f32x2v accAa = {0.0f,0.0f}, accBa = {0.0f,0.0f};
    f32x2v accAb = {0.0f,0.0f}, accBb = {0.0f,0.0f};
#pragma unroll
    for (int m = 0; m < 8; ++m) {
        f32x2v wp; wp[0] = w3m[2*m]; wp[1] = w3m[2*m+1];
        accAa = wp * sigp(a1a[2*m], a1a[2*m+1]) + accAa;
        accBa = wp * sigp(a2a[2*m], a2a[2*m+1]) + accBa;
        accAb = wp * sigp(a1b[2*m], a1b[2*m+1]) + accAb;
        accBb = wp * sigp(a2b[2*m], a2b[2*m+1]) + accBb;
    }
    float pAa = accAa[0] + accAa[1], pBa = accBa[0] + accBa[1];
    float pAb = accAb[0] + accAb[1], pBb = accBb[0] + accBb[1];
    auto ca = __builtin_amdgcn_permlane32_swap(__float_as_int(pAa), __float_as_int(pBa), false, false);
    auto cb = __builtin_amdgcn_permlane32_swap(__float_as_int(pAb), __float_as_int(pBb), false, false);
    float oa = o0 + __int_as_float(ca[0]) + __int_as_float(ca[1]);
    float ob = o0 + __int_as_float(cb[0]) + __int_as_float(cb[1]);
    f32x2v out;
    out[0] = __logf(1.0f + __expf(oa));
    out[1] = __logf(1.0f + __expf(ob));
    return out;
}

__global__ __launch_bounds__(256) void gamma_rk4_mfma(
        const float4* __restrict__ inp, const float* __restrict__ gamma,
        const float* __restrict__ W1, const float* __restrict__ b1,
        const float* __restrict__ W2, const float* __restrict__ b2,
        const float* __restrict__ W3, const float* __restrict__ b3,
        float* __restrict__ out, int B)
{
    int idx  = blockIdx.x * 256 + threadIdx.x;
    int lane = threadIdx.x & 63;
    int hi   = lane >> 5;
    int arow = lane & 31;

    // L1 A-frag: A = c*W1 in f16; k0=c*W1[0][j], k1=c*W1[1][j]; hi lanes zero
    f16x8 A1;
    {
        unsigned p10 = cvtpk_u(C2LE * W1[arow], C2LE * W1[32 + arow]);
        A1 = hi ? mk_frag(0u, 0u, 0u, 0u) : mk_frag(p10, 0u, 0u, 0u);
    }
    // L2 A' = -2c*W2^T in f16 (two K=16 chunks)
    f16x8 A2[2];
#pragma unroll
    for (int s = 0; s < 2; ++s) {
        unsigned w[4];
#pragma unroll
        for (int m = 0; m < 4; ++m) {
            w[m] = cvtpk_u(NEG2C * W2[(16*s + 8*hi + 2*m    ) * 32 + arow],
                           NEG2C * W2[(16*s + 8*hi + 2*m + 1) * 32 + arow]);
        }
        A2[s] = mk_frag(w[0], w[1], w[2], w[3]);
    }
    // C/D row map: row = (r&3) + 8*(r>>2) + 4*hi
    f32x16 cb1v, cb2v, w3m;
    float wsum = 0.0f;
#pragma unroll
    for (int r = 0; r < 16; ++r) {
        int row = (r & 3) + 8 * (r >> 2) + 4 * hi;
        cb1v[r] = C2LE * b1[row];
        cb2v[r] = C2LE * b2[row];
        float w3 = W3[row];
        w3m[r] = -2.0f * w3;
        wsum  += w3;
    }
    // cb2v += c*colsum(W2) via MFMA with B = -0.5 (exact in f16: 0xB800)
    {
        unsigned nh = 0xB800B800u;
        f16x8 negh = mk_frag(nh, nh, nh, nh);
        cb2v = __builtin_amdgcn_mfma_f32_32x32x16_f16(A2[0], negh, cb2v, 0, 0, 0);
        cb2v = __builtin_amdgcn_mfma_f32_32x32x16_f16(A2[1], negh, cb2v, 0, 0, 0);
    }
    auto sw = __builtin_amdgcn_permlane32_swap(__float_as_int(wsum), __float_as_int(wsum), false, false);
    float o0 = b3[0] + __int_as_float(sw[0]) + __int_as_float(sw[1]);

    int i0 = 2 * idx;
    if (i0 >= B) return;
    float4 va = inp[i0];
    float4 vb = inp[i0 + 1];
    float2 gg = *reinterpret_cast<const float2*>(gamma + i0);

    f32x2v g0v = {gg.x, gg.y};
    f32x2v e_n = {va.x, vb.x}, e_h = {va.y, vb.y}, e_o = {va.z, vb.z};
    f32x2v dt  = {va.w, vb.w};

    f32x2v k1 = dt * mlp_f2(e_n, g0v, A1, cb1v, A2[0], A2[1], cb2v, w3m, o0) * (e_n - g0v);
    f32x2v g1 = 0.5f * k1 + g0v;
    f32x2v k2 = dt * mlp_f2(e_h, g1,  A1, cb1v, A2[0], A2[1], cb2v, w3m, o0) * (e_h - g1);
    f32x2v g2 = 0.5f * k2 + g0v;
    f32x2v k3 = dt * mlp_f2(e_h, g2,  A1, cb1v, A2[0], A2[1], cb2v, w3m, o0) * (e_h - g2);
    f32x2v g3 = g0v + k3;
    f32x2v k4 = dt * mlp_f2(e_o, g3,  A1, cb1v, A2[0], A2[1], cb2v, w3m, o0) * (e_o - g3);

    f32x2v res = g0v + (k1 + 2.0f * (k2 + k3) + k4) * (1.0f / 6.0f);
    float2 ro; ro.x = res[0]; ro.y = res[1];
    *reinterpret_cast<float2*>(out + i0) = ro;
}

extern "C" void kernel_launch(void* const* d_in, const int* in_sizes, int n_in,
                              void* d_out, int out_size, void* d_ws, size_t ws_size,
                              hipStream_t stream) {
    const float4* inp   = (const float4*)d_in[0];
    const float*  gamma = (const float*)d_in[1];
    const float*  W1    = (const float*)d_in[2];
    const float*  b1    = (const float*)d_in[3];
    const float*  W2    = (const float*)d_in[4];
    const float*  b2    = (const float*)d_in[5];
    const float*  W3    = (const float*)d_in[6];
    const float*  b3    = (const float*)d_in[7];
    float* out = (float*)d_out;

    int B = in_sizes[1];
    int threads = (B + 1) / 2;
    int block = 256;
    int grid = (threads + block - 1) / block;
    gamma_rk4_mfma<<<grid, block, 0, stream>>>(inp, gamma, W1, b1, W2, b2,
                                               W3, b3, out, B);
}